// Round 9
// baseline (4568.093 us; speedup 1.0000x reference)
//
#include <hip/hip_runtime.h>
#include <stdint.h>

#define B_ 64
#define T_ 512
#define I_ 256
#define H_ 512
#define NTHR_ 256
#define D_ 8   // ring depth in CYC fallback mode

typedef __attribute__((ext_vector_type(8))) short short8;
typedef __attribute__((ext_vector_type(4))) float float4v;
typedef __attribute__((ext_vector_type(4))) unsigned int uint4v;
typedef __attribute__((ext_vector_type(2))) unsigned int uint2v;

static_assert(sizeof(short8) == 16, "");

#define TILE_B 2048                       // per (bg,ktile): 1KB hi + 1KB lo frags
#define SLOT_B ((size_t)4 * 16 * TILE_B)  // 128 KB per slot

// ---- bf16 helpers (round-to-nearest-even) ----
__device__ __forceinline__ unsigned short f2bf(float x) {
  union { float f; uint32_t u; } v; v.f = x;
  uint32_t r = v.u + 0x7FFFu + ((v.u >> 16) & 1u);
  return (unsigned short)(r >> 16);
}
__device__ __forceinline__ float bf2f(unsigned short h) {
  union { uint32_t u; float f; } v; v.u = ((uint32_t)h) << 16; return v.f;
}
__device__ __forceinline__ void splitHL(float x, unsigned short& hi, unsigned short& lo) {
  hi = f2bf(x);
  lo = f2bf(x - bf2f(hi));   // x - hi is exact in fp32
}

// byte offset of a lane's hi-frag; lo-frag at +1024 (same tile)
__device__ __forceinline__ size_t rbyte(int slot, int bg, int ht, int lane) {
  return ((size_t)slot * 64 + bg * 16 + ht) * TILE_B + (size_t)lane * 16;
}

#define MFMA16(A, Bv, C) __builtin_amdgcn_mfma_f32_16x16x32_bf16(A, Bv, C, 0, 0, 0)

// counted wait on our asm-issued vmem + scheduling fence (rule #18)
#define WAITV(n) do { \
    asm volatile("s_waitcnt vmcnt(" #n ")" ::: "memory"); \
    __builtin_amdgcn_sched_barrier(0); \
  } while (0)
#define SB() __builtin_amdgcn_sched_barrier(0)

// One LSTM layer; each WAVE is an independent agent: batch-group bg, full K.
// Block 'a' owns h-columns [4a,4a+4) -> 16 gate cols. K: [0,K1)=inp, [K1,K1+512)=h.
// MFMA frags: k(q,j)=4q+(j&3)+16*(j>>2); A-row=lane&15, B-col=lane&15,
// C/D col=lane&15 row=4*(lane>>4)+i (m89-verified).
//
// FULL: write-once rings (T+1 slots, slot s = h[s-1], slot0 zeroed); plain
// cached ring reads (all reads flag-gated -> first L2 fill always fresh).
// CYC (fallback): D=8 circular slots, sc0 sc1 bypass reads, +backpressure poll.
// Flags: prog[layer][bg][a], per-wave stores (never RMW). Poll: each lane
// dwordx2-loads 2 words, __all; own word skipped (own data ordered by program
// order: stores drained via vmcnt(0) before flag store at t-1).
template <int LAYER, bool FULL>
__device__ void run_layer4(
    int a,
    const float* __restrict__ x,
    const float* __restrict__ Wxp, const float* __restrict__ bxp,
    const float* __restrict__ Whp,
    uint32_t* prog0, uint32_t* prog1,
    uint8_t* r0, uint8_t* r1,
    float* h1f,
    unsigned short* WshHi, unsigned short* WshLo)
{
  constexpr int K1 = LAYER ? H_ : I_;
  constexpr int NT = (K1 + H_) / 32;   // 24 (L0) or 32 (L1) K-tiles, full K per wave
  const int tid = threadIdx.x;         // 0..255
  const int lane = tid & 63;
  const int bg = tid >> 6;             // wave id == batch group
  const int qq = lane >> 4;
  const int cc = lane & 15;
  const int brow = bg * 16 + cc;

  // ---- stage weights: hi AND lo both to LDS (one pass) ----
  for (int idx = tid; idx < NT * 512; idx += NTHR_) {
    int tile = idx >> 9, r = idx & 511, ln = r >> 3, j = r & 7;
    int k = tile * 32 + 4 * (ln >> 4) + (j & 3) + 16 * (j >> 2);
    int n = 4 * a + (ln & 3);
    int g = (ln & 15) >> 2;
    float wvv = (k < K1) ? Wxp[((size_t)g * K1 + k) * H_ + n]
                         : Whp[((size_t)g * H_ + (k - K1)) * H_ + n];
    unsigned short hi, lo; splitHL(wvv, hi, lo);
    WshHi[idx] = hi; WshLo[idx] = lo;
  }
  __syncthreads();   // last block-wide barrier; T-loop below is barrier-free

  const float biasv = bxp[(size_t)(cc >> 2) * H_ + 4 * a + (cc & 3)];
  float cst[4] = {0.f, 0.f, 0.f, 0.f};

  uint32_t* myflag = (LAYER ? prog1 : prog0) + bg * 128 + a;
  const uint32_t* g0 = prog0 + bg * 128;
  const uint32_t* g1 = prog1 + bg * 128;
  const bool skip0 = (2 * lane == a), skip1 = (2 * lane + 1 == a);

  // wave-collective poll: lane l checks words 2l,2l+1 of the 128-word group
  auto poll = [&](const uint32_t* grp, int tgt, bool useSkip) {
    if (tgt <= 0) return;
    const unsigned long long* p = (const unsigned long long*)grp + lane;
    int it = 0;
    while (true) {
      unsigned long long v = __hip_atomic_load(p, __ATOMIC_RELAXED,
                                               __HIP_MEMORY_SCOPE_AGENT);
      bool ok = ((useSkip && skip0) || (int)(uint32_t)v >= tgt) &&
                ((useSkip && skip1) || (int)(uint32_t)(v >> 32) >= tgt);
      if (__all((int)ok)) return;
      __builtin_amdgcn_s_sleep(1);
      if (++it > 2000000) return;   // degrade to wrong answer, never hang
    }
  };

  for (int t = 0; t < T_; ++t) {
    const int slotP = FULL ? t       : (t & (D_ - 1));        // h[t-1]
    const int slotC = FULL ? (t + 1) : ((t + 1) & (D_ - 1));  // h[t]
    float4v accA = {biasv, biasv, biasv, biasv};  // hi*Whi (+bias)
    float4v accB = {0.f, 0.f, 0.f, 0.f};          // lo*Whi
    float4v accC = {0.f, 0.f, 0.f, 0.f};          // hi*Wlo

    short8 hb[8], lb[8], hb2[8], lb2[8];

    auto issue_tile = [&](short8* hd, short8* ld, int tile) {
      const uint8_t* p;
      if (!LAYER)        p = r0 + rbyte(slotP, bg, tile - 8, lane);
      else if (tile < 16) p = r0 + rbyte(slotC, bg, tile, lane);
      else                p = r1 + rbyte(slotP, bg, tile - 16, lane);
      if constexpr (FULL) {
        asm volatile("global_load_dwordx4 %0, %2, off\n\t"
                     "global_load_dwordx4 %1, %2, off offset:1024"
                     : "=&v"(*hd), "=&v"(*ld) : "v"(p) : "memory");
      } else {
        asm volatile("global_load_dwordx4 %0, %2, off sc0 sc1\n\t"
                     "global_load_dwordx4 %1, %2, off offset:1024 sc0 sc1"
                     : "=&v"(*hd), "=&v"(*ld) : "v"(p) : "memory");
      }
    };
    auto proc_tile = [&](short8 h, short8 l, int tile) {
      short8 bhi = *(const short8*)(WshHi + tile * 512 + lane * 8);
      short8 blo = *(const short8*)(WshLo + tile * 512 + lane * 8);
      accA = MFMA16(h, bhi, accA);
      accB = MFMA16(l, bhi, accB);
      accC = MFMA16(h, blo, accC);
    };

    if constexpr (!LAYER) {
      uint4v xw0[8], xw1[8];
      #pragma unroll
      for (int u = 0; u < 8; ++u) {     // x read-only: cached loads
        const float* xp = x + ((size_t)brow * T_ + t) * I_ + u * 32 + 4 * qq;
        asm volatile("global_load_dwordx4 %0, %2, off\n\t"
                     "global_load_dwordx4 %1, %2, off offset:64"
                     : "=&v"(xw0[u]), "=&v"(xw1[u]) : "v"(xp) : "memory");
      }
      poll(g0, t, true);                             // drains x loads too
      if constexpr (!FULL) poll(g1, t - (D_ - 1), false);  // CYC backpressure
      WAITV(0);
      #pragma unroll
      for (int u = 0; u < 8; ++u) issue_tile(&hb[u],  &lb[u],  8 + u);
      #pragma unroll
      for (int u = 0; u < 8; ++u) issue_tile(&hb2[u], &lb2[u], 16 + u);
      SB();
      #pragma unroll
      for (int u = 0; u < 8; ++u) {     // convert+MFMA x under ring flight
        short8 ahi, alo;
        #pragma unroll
        for (int j = 0; j < 4; ++j) {
          unsigned short hh, ll;
          splitHL(__uint_as_float(xw0[u][j]), hh, ll); ahi[j] = (short)hh; alo[j] = (short)ll;
          splitHL(__uint_as_float(xw1[u][j]), hh, ll); ahi[j + 4] = (short)hh; alo[j + 4] = (short)ll;
        }
        proc_tile(ahi, alo, u);
      }
      WAITV(16);
      #pragma unroll
      for (int u = 0; u < 8; ++u) proc_tile(hb[u], lb[u], 8 + u);
      WAITV(0);
      #pragma unroll
      for (int u = 0; u < 8; ++u) proc_tile(hb2[u], lb2[u], 16 + u);
    } else {
      short8 hb3[8], lb3[8], hb4[8], lb4[8];
      poll(g0, t + 1, false);           // L0 runs ahead -> usually instant
      SB();
      #pragma unroll
      for (int u = 0; u < 8; ++u) issue_tile(&hb[u],  &lb[u],  u);      // h0 tiles
      #pragma unroll
      for (int u = 0; u < 8; ++u) issue_tile(&hb2[u], &lb2[u], 8 + u);
      poll(g1, t, true);                // the real wait; drains ring0 loads
      WAITV(0);
      #pragma unroll
      for (int u = 0; u < 8; ++u) issue_tile(&hb3[u], &lb3[u], 16 + u); // h1 tiles
      SB();
      #pragma unroll
      for (int u = 0; u < 8; ++u) proc_tile(hb[u], lb[u], u);           // under flight
      #pragma unroll
      for (int u = 0; u < 8; ++u) issue_tile(&hb4[u], &lb4[u], 24 + u);
      SB();
      #pragma unroll
      for (int u = 0; u < 8; ++u) proc_tile(hb2[u], lb2[u], 8 + u);
      WAITV(16);
      #pragma unroll
      for (int u = 0; u < 8; ++u) proc_tile(hb3[u], lb3[u], 16 + u);
      WAITV(0);
      #pragma unroll
      for (int u = 0; u < 8; ++u) proc_tile(hb4[u], lb4[u], 24 + u);
    }

    float4v acc = accA + accB + accC;

    // ---- epilogue: wave-local (no split-K, no LDS reduce, no barriers) ----
    const bool isg = cc >= 12;
    float av[4];
    #pragma unroll
    for (int i = 0; i < 4; ++i) {
      float xg = acc[i];
      float arg = isg ? xg + xg : xg;
      float e = __expf(-fabsf(arg));
      float s = (arg >= 0.f) ? 1.f / (1.f + e) : e / (1.f + e);
      av[i] = isg ? (s + s - 1.f) : s;   // tanh(x) = 2*sigmoid(2x)-1
    }
    float hn[4];
    #pragma unroll
    for (int i = 0; i < 4; ++i) {
      float fv = __shfl_xor(av[i], 4);
      float ov = __shfl_xor(av[i], 8);
      float gv = __shfl_xor(av[i], 12);
      float cn = fv * cst[i] + av[i] * gv;
      cst[i] = cn;
      float e2 = __expf(-2.f * fabsf(cn));
      float th = (1.f - e2) / (1.f + e2);
      hn[i] = ov * ((cn >= 0.f) ? th : -th);
    }
    // in-wave transpose: lane (qq,cc<4) gathers row 4qq+cc, cols 4a+0..3
    float v0[4], v1[4], v2[4], v3[4];
    #pragma unroll
    for (int d = 0; d < 4; ++d) {
      int src = (lane & 0x30) | d;
      v0[d] = __shfl(hn[0], src);
      v1[d] = __shfl(hn[1], src);
      v2[d] = __shfl(hn[2], src);
      v3[d] = __shfl(hn[3], src);
    }
    if (cc < 4) {
      unsigned short hh[4], ll[4]; float4v hf;
      #pragma unroll
      for (int d = 0; d < 4; ++d) {
        float hv = (cc == 0) ? v0[d] : (cc == 1) ? v1[d] : (cc == 2) ? v2[d] : v3[d];
        hf[d] = hv;
        splitHL(hv, hh[d], ll[d]);
      }
      uint2v hi2, lo2;
      hi2[0] = (uint32_t)hh[0] | ((uint32_t)hh[1] << 16);
      hi2[1] = (uint32_t)hh[2] | ((uint32_t)hh[3] << 16);
      lo2[0] = (uint32_t)ll[0] | ((uint32_t)ll[1] << 16);
      lo2[1] = (uint32_t)ll[2] | ((uint32_t)ll[3] << 16);
      // frag store: lane' = 16*(a&3)+(4qq+cc), shorts j0..j0+3, j0=4*((a>>2)&1)
      uint8_t* dst = (LAYER ? r1 : r0)
                   + rbyte(slotC, bg, a >> 3, 16 * (a & 3) + 4 * qq + cc)
                   + 8 * ((a >> 2) & 1);
      asm volatile("global_store_dwordx2 %0, %1, off sc0 sc1\n\t"
                   "global_store_dwordx2 %0, %2, off offset:1024 sc0 sc1"
                   :: "v"(dst), "v"(hi2), "v"(lo2) : "memory");
      if (LAYER && t == T_ - 1) {
        float4v* hp = (float4v*)(h1f + (size_t)(bg * 16 + 4 * qq + cc) * H_ + 4 * a);
        asm volatile("global_store_dwordx4 %0, %1, off sc0 sc1"
                     :: "v"(hp), "v"(hf) : "memory");
      }
    }
    // per-wave publish: drain own stores (acked at coherence point) -> flag
    asm volatile("s_waitcnt vmcnt(0)" ::: "memory");
    if (lane == 0)
      __hip_atomic_store(myflag, (uint32_t)(t + 1),
                         __ATOMIC_RELAXED, __HIP_MEMORY_SCOPE_AGENT);
  }
}

template <bool FULL>
__global__ __launch_bounds__(NTHR_, 1) void lstm_persist4(
    const float* __restrict__ x,
    const float* __restrict__ Wx0, const float* __restrict__ bx0, const float* __restrict__ Wh0,
    const float* __restrict__ Wx1, const float* __restrict__ bx1, const float* __restrict__ Wh1,
    uint32_t* prog0, uint32_t* prog1,
    uint8_t* ring0, uint8_t* ring1,
    float* h1f)
{
  __shared__ unsigned short WshHi[16384];  // 32 KB
  __shared__ unsigned short WshLo[16384];  // 32 KB
  if (blockIdx.x < 128)
    run_layer4<0, FULL>(blockIdx.x, x, Wx0, bx0, Wh0, prog0, prog1, ring0, ring1, h1f, WshHi, WshLo);
  else
    run_layer4<1, FULL>(blockIdx.x - 128, x, Wx1, bx1, Wh1, prog0, prog1, ring0, ring1, h1f, WshHi, WshLo);
}

__global__ void fc_out(const float* __restrict__ h1f, const float* __restrict__ Wfc,
                       const float* __restrict__ bfc, float* __restrict__ out)
{
  int tid = threadIdx.x;
  int b = tid >> 3, p = tid & 7;
  const float* hp = h1f + (size_t)b * H_ + p * 64;
  const float* wp = Wfc + p * 64;
  float4v hv[16];
  #pragma unroll
  for (int q = 0; q < 16; ++q)
    asm volatile("global_load_dwordx4 %0, %1, off sc0 sc1"
                 : "=&v"(hv[q]) : "v"(hp + 4 * q) : "memory");
  asm volatile("s_waitcnt vmcnt(0)" ::: "memory");
  float s = 0.f;
  #pragma unroll
  for (int q = 0; q < 16; ++q) {
    float4v wv = *(const float4v*)(wp + 4 * q);
    s += hv[q][0] * wv[0] + hv[q][1] * wv[1] + hv[q][2] * wv[2] + hv[q][3] * wv[3];
  }
  s += __shfl_xor(s, 1);
  s += __shfl_xor(s, 2);
  s += __shfl_xor(s, 4);
  if (p == 0) out[b] = s + bfc[0];
}

extern "C" void kernel_launch(void* const* d_in, const int* in_sizes, int n_in,
                              void* d_out, int out_size, void* d_ws, size_t ws_size,
                              hipStream_t stream)
{
  const float* x   = (const float*)d_in[0];
  const float* Wx0 = (const float*)d_in[1];
  const float* bx0 = (const float*)d_in[2];
  const float* Wh0 = (const float*)d_in[3];
  const float* Wx1 = (const float*)d_in[4];
  const float* bx1 = (const float*)d_in[5];
  const float* Wh1 = (const float*)d_in[6];
  const float* Wfc = (const float*)d_in[7];
  const float* bfc = (const float*)d_in[8];

  uint8_t* ws = (uint8_t*)d_ws;
  const size_t RINGB_FULL = (size_t)(T_ + 1) * SLOT_B;   // 65.7 MB per ring
  const size_t RINGB_CYC  = (size_t)D_ * SLOT_B;         // 1 MB per ring
  const size_t NEED_FULL  = 4096 + 2 * RINGB_FULL + (size_t)B_ * H_ * 4;

  // flags: prog[layer][bg][a] -> 2 x 4 x 128 u32 = 4 KB exactly
  uint32_t* prog0 = (uint32_t*)ws;
  uint32_t* prog1 = (uint32_t*)(ws + 2048);

  if (ws_size >= NEED_FULL) {
    uint8_t* ring0 = ws + 4096;
    uint8_t* ring1 = ws + 4096 + RINGB_FULL;
    float* h1f = (float*)(ws + 4096 + 2 * RINGB_FULL);
    (void)hipMemsetAsync(ws, 0, 4096 + SLOT_B, stream);   // flags + ring0 slot0
    (void)hipMemsetAsync(ring1, 0, SLOT_B, stream);       // ring1 slot0
    hipLaunchKernelGGL(lstm_persist4<true>, dim3(256), dim3(NTHR_), 0, stream,
                       x, Wx0, bx0, Wh0, Wx1, bx1, Wh1,
                       prog0, prog1, ring0, ring1, h1f);
    hipLaunchKernelGGL(fc_out, dim3(1), dim3(512), 0, stream,
                       h1f, Wfc, bfc, (float*)d_out);
  } else {
    uint8_t* ring0 = ws + 4096;
    uint8_t* ring1 = ws + 4096 + RINGB_CYC;
    float* h1f = (float*)(ws + 4096 + 2 * RINGB_CYC);
    (void)hipMemsetAsync(ws, 0, 4096 + 2 * RINGB_CYC, stream);
    hipLaunchKernelGGL(lstm_persist4<false>, dim3(256), dim3(NTHR_), 0, stream,
                       x, Wx0, bx0, Wh0, Wx1, bx1, Wh1,
                       prog0, prog1, ring0, ring1, h1f);
    hipLaunchKernelGGL(fc_out, dim3(1), dim3(512), 0, stream,
                       h1f, Wfc, bfc, (float*)d_out);
  }
}